// Round 11
// baseline (2579.318 us; speedup 1.0000x reference)
//
#include <hip/hip_runtime.h>
#include <hip/hip_bf16.h>

// BasicLSTM: B=64, T=512, D=512, U=1024.  out = h_last [64][1024] f32.
// Round 11: tag-in-data exchange, NO barrier/flags. hbuf is u32 =
// (step_tag<<16)|bf16_h, double-buffered by step parity. Producers
// fire-and-forget sc0sc1 stores; consumers' stage loads spin until all
// 16 tags in their chunk match step s. All-to-all mutual consumption
// within a group bounds skew to 1 step -> double buffer is safe.
// Groups: 8 groups x 8 batch rows; 32 z-blocks each (256 blocks total).

#define T_STEPS 512
#define BATCH   64
#define DIM     512
#define UNITS   1024
#define ZCOLS   4096

typedef float        f32x4 __attribute__((ext_vector_type(4)));
typedef unsigned int u32x4 __attribute__((ext_vector_type(4)));

__device__ __forceinline__ f32x4 mfma16x16x32_bf16(u32x4 a, u32x4 b, f32x4 c) {
    asm("v_mfma_f32_16x16x32_bf16 %0, %1, %2, %0" : "+v"(c) : "v"(a), "v"(b));
    return c;
}

__device__ __forceinline__ unsigned short f2bf(float f) {
    union { float f; unsigned u; } v; v.f = f;
    unsigned r = v.u + 0x7fffu + ((v.u >> 16) & 1u);   // RNE
    return (unsigned short)(r >> 16);
}

__device__ __forceinline__ float fsigmoid(float x) { return 1.0f / (1.0f + __expf(-x)); }
__device__ __forceinline__ float ftanh(float x)    { return 1.0f - 2.0f / (__expf(2.0f * x) + 1.0f); }

__device__ __forceinline__ u32x4 pack8(const float* __restrict__ p) {
    float4 f0 = reinterpret_cast<const float4*>(p)[0];
    float4 f1 = reinterpret_cast<const float4*>(p)[1];
    u32x4 r;
    r.x = (unsigned)f2bf(f0.x) | ((unsigned)f2bf(f0.y) << 16);
    r.y = (unsigned)f2bf(f0.z) | ((unsigned)f2bf(f0.w) << 16);
    r.z = (unsigned)f2bf(f1.x) | ((unsigned)f2bf(f1.y) << 16);
    r.w = (unsigned)f2bf(f1.z) | ((unsigned)f2bf(f1.w) << 16);
    return r;
}

#define LDX4T(d, p) \
    asm volatile("global_load_dwordx4 %0, %1, off sc0 sc1" : "=v"(d) : "v"(p));
#define WAITV0 \
    asm volatile("s_waitcnt vmcnt(0)" ::: "memory"); \
    __builtin_amdgcn_sched_barrier(0);

// ---------------- prep kernels ----------------

__global__ void k_transpose_bf16(const float* __restrict__ in, unsigned short* __restrict__ out,
                                 int K, int N) {
    __shared__ float tile[32][33];
    int n0 = blockIdx.x * 32, k0 = blockIdx.y * 32;
    int tx = threadIdx.x, ty = threadIdx.y;
    tile[ty][tx] = in[(size_t)(k0 + ty) * N + n0 + tx];
    __syncthreads();
    out[(size_t)(n0 + ty) * K + k0 + tx] = f2bf(tile[tx][ty]);
}

__global__ void k_init(unsigned int* __restrict__ hbuf_u32, float* __restrict__ cbuf) {
    int i = blockIdx.x * blockDim.x + threadIdx.x;       // 512*512 threads
    if (i < 131072) hbuf_u32[i] = 0u;                    // 2*64*1024 u32 (tag0|h=0)
    else if (i < 196608) cbuf[i - 131072] = 0.0f;        // 64*1024 f32
}

// ---------------- phase 1: xz(chunk) = x_t @ Wx + b (proven R8/R9) ----------------
__global__ __launch_bounds__(512, 2) void k_xproj(
        const float* __restrict__ x,
        const unsigned short* __restrict__ WxT,   // [4096][512]
        const float* __restrict__ bias,
        float* __restrict__ xz,                   // [T_c][64][4096]
        int base) {
    const int tid  = threadIdx.x;
    const int lane = tid & 63;
    const int w    = tid >> 6;
    const int n0   = blockIdx.x * 512 + w * 64;
    const int t    = blockIdx.y;
    const int r16  = lane & 15;
    const int kl   = (lane >> 4) * 8;

    __shared__ __align__(16) unsigned short as_[64 * 512];   // 64 KB

    for (int i = tid; i < 4096; i += 512) {
        int row = i >> 6, kc = i & 63;
        u32x4 v = pack8(x + ((size_t)row * T_STEPS + base + t) * DIM + kc * 8);
        int lb = (row * 1024 + kc * 16) ^ ((row & 7) << 4);
        *reinterpret_cast<u32x4*>(reinterpret_cast<char*>(as_) + lb) = v;
    }
    __syncthreads();

    const unsigned short* bp = WxT + (size_t)(n0 + r16) * DIM + kl;

    f32x4 acc[4][4] = {};
    asm volatile("s_nop 1" : "+v"(acc[0][0]), "+v"(acc[1][1]), "+v"(acc[2][2]), "+v"(acc[3][3]));

    #pragma unroll 2
    for (int kk = 0; kk < 16; ++kk) {
        u32x4 b0 = *reinterpret_cast<const u32x4*>(bp + kk * 32);
        u32x4 b1 = *reinterpret_cast<const u32x4*>(bp + 16 * DIM + kk * 32);
        u32x4 b2 = *reinterpret_cast<const u32x4*>(bp + 32 * DIM + kk * 32);
        u32x4 b3 = *reinterpret_cast<const u32x4*>(bp + 48 * DIM + kk * 32);
        u32x4 a[4];
        #pragma unroll
        for (int mt = 0; mt < 4; ++mt) {
            int row = mt * 16 + r16;
            int lb = (row * 1024 + (kk * 32 + kl) * 2) ^ ((row & 7) << 4);
            a[mt] = *reinterpret_cast<const u32x4*>(reinterpret_cast<const char*>(as_) + lb);
        }
        #pragma unroll
        for (int mt = 0; mt < 4; ++mt) {
            acc[mt][0] = mfma16x16x32_bf16(a[mt], b0, acc[mt][0]);
            acc[mt][1] = mfma16x16x32_bf16(a[mt], b1, acc[mt][1]);
            acc[mt][2] = mfma16x16x32_bf16(a[mt], b2, acc[mt][2]);
            acc[mt][3] = mfma16x16x32_bf16(a[mt], b3, acc[mt][3]);
        }
    }
    asm volatile("s_nop 7\n\ts_nop 7" : "+v"(acc[0][0]), "+v"(acc[1][1]), "+v"(acc[2][2]), "+v"(acc[3][3]));

    const int rowq = (lane >> 4) * 4;
    #pragma unroll
    for (int nt = 0; nt < 4; ++nt) {
        const int col = n0 + nt * 16 + r16;
        const float bv = bias[col];
        #pragma unroll
        for (int mt = 0; mt < 4; ++mt)
            #pragma unroll
            for (int r = 0; r < 4; ++r)
                xz[((size_t)t * BATCH + mt * 16 + rowq + r) * ZCOLS + col] = acc[mt][nt][r] + bv;
    }
}

// ---------------- phase 2: recurrence, tag-in-data exchange ----------------
// 256 blocks x 512 thr. Block (grp=bid&7, zs=bid>>3): rows [8grp,+8),
// units [32zs,+32) x 4 gates. Waves: ct=w&3 (gate), kh=w>>2 (K-half).
// MFMA M=16 with A rows c16&7 (rows 8-15 duplicate rows 0-7).
__global__ __launch_bounds__(512, 1) void k_lstm(
        const float* __restrict__ xz,            // [T_c][64][4096], bias folded
        const unsigned short* __restrict__ WhT,  // [4096][1024]
        unsigned int* hbuf,                      // [2][64][1024] u32 tagged
        float* __restrict__ cbuf,                // [64][1024] f32
        float* __restrict__ out,                 // [64][1024] f32
        int base_step, int tc) {
    const int tid  = threadIdx.x;
    const int lane = tid & 63;
    const int w    = tid >> 6;          // 0..7
    const int ct   = w & 3;             // gate
    const int kh   = w >> 2;            // K half
    const int grp  = blockIdx.x & 7;
    const int zs   = blockIdx.x >> 3;
    const int r0   = grp * 8;
    const int u0   = zs * 32;
    const int c16  = lane & 15;
    const int klb  = (lane >> 4) * 16;  // k byte offset within 64B kk-chunk

    __shared__ __align__(16) unsigned short hs[8 * 1024];    // 16 KB, swizzled
    __shared__ float zb[32 * 132];                           // 16.9 KB

    // Wh slice: breg[n][kk] = WhT row (ct*1024 + u0 + n*16 + c16),
    // k = kh*512 + kk*32 + (lane>>4)*8   (plain cached loads; L1-resident)
    u32x4 breg[2][16];
    #pragma unroll
    for (int n = 0; n < 2; ++n) {
        const unsigned short* wp =
            WhT + ((size_t)(ct * UNITS + u0 + n * 16 + c16)) * UNITS + kh * 512 + (lane >> 4) * 8;
        #pragma unroll
        for (int kk = 0; kk < 16; ++kk) {
            breg[n][kk] = *reinterpret_cast<const u32x4*>(wp + kk * 32);
            asm volatile("" : "+v"(breg[n][kk]));
        }
    }

    // gate identity (tid<256): row r0+ri, unit u0+ui
    const int ri = tid >> 5;            // 0..7
    const int ui = tid & 31;            // 0..31
    float creg = 0.0f;
    if (tid < 256) creg = cbuf[(size_t)(r0 + ri) * UNITS + u0 + ui];

    // stage identity: thread = one 16-unit chunk of one row
    const int srow  = tid >> 6;         // 0..7
    const int scol0 = (tid & 63) * 16;  // 0..1008
    const int sbase = srow * 2048 + scol0 * 2;
    const int sxor  = (srow & 7) << 4;

    for (int t = 0; t < tc; ++t) {
        const int s = base_step + t;

        // --- stage h(s): tag-polled loads -> swizzled LDS (bf16) ---
        {
            const unsigned int* sp = hbuf + (size_t)(s & 1) * (BATCH * UNITS)
                                     + (size_t)(r0 + srow) * UNITS + scol0;
            const unsigned want = (unsigned)s;
            u32x4 v0, v1, v2, v3;
            int iter = 0;
            for (;;) {
                LDX4T(v0, sp) LDX4T(v1, sp + 4) LDX4T(v2, sp + 8) LDX4T(v3, sp + 12)
                WAITV0
                bool ok = ((v0.x >> 16) == want) & ((v0.y >> 16) == want) &
                          ((v0.z >> 16) == want) & ((v0.w >> 16) == want) &
                          ((v1.x >> 16) == want) & ((v1.y >> 16) == want) &
                          ((v1.z >> 16) == want) & ((v1.w >> 16) == want) &
                          ((v2.x >> 16) == want) & ((v2.y >> 16) == want) &
                          ((v2.z >> 16) == want) & ((v2.w >> 16) == want) &
                          ((v3.x >> 16) == want) & ((v3.y >> 16) == want) &
                          ((v3.z >> 16) == want) & ((v3.w >> 16) == want);
                if (ok) break;
                if (++iter > (1 << 16)) break;   // fail loud, never hang
                __builtin_amdgcn_s_sleep(1);
            }
            u32x4 A, B;
            A.x = (v0.x & 0xffffu) | (v0.y << 16);
            A.y = (v0.z & 0xffffu) | (v0.w << 16);
            A.z = (v1.x & 0xffffu) | (v1.y << 16);
            A.w = (v1.z & 0xffffu) | (v1.w << 16);
            B.x = (v2.x & 0xffffu) | (v2.y << 16);
            B.y = (v2.z & 0xffffu) | (v2.w << 16);
            B.z = (v3.x & 0xffffu) | (v3.y << 16);
            B.w = (v3.z & 0xffffu) | (v3.w << 16);
            *reinterpret_cast<u32x4*>(reinterpret_cast<char*>(hs) + (sbase ^ sxor))        = A;
            *reinterpret_cast<u32x4*>(reinterpret_cast<char*>(hs) + ((sbase + 16) ^ sxor)) = B;
        }
        __syncthreads();

        // xz prefetch (cached; drains during MFMA)
        float xv0 = 0, xv1 = 0, xv2 = 0, xv3 = 0;
        if (tid < 256) {
            const float* xp = xz + ((size_t)t * BATCH + r0 + ri) * ZCOLS + u0 + ui;
            xv0 = xp[0]; xv1 = xp[UNITS]; xv2 = xp[2 * UNITS]; xv3 = xp[3 * UNITS];
        }

        // --- MFMA: A rows = c16&7 (rows 8-15 duplicate), B in regs ---
        f32x4 acc0 = {0, 0, 0, 0}, acc1 = {0, 0, 0, 0};
        asm volatile("s_nop 1" : "+v"(acc0), "+v"(acc1));
        const char* abase = reinterpret_cast<const char*>(hs);
        const int axor = (c16 & 7) << 4;
        const int aoff = (c16 & 7) * 2048 + kh * 1024 + klb;
        #pragma unroll
        for (int kk = 0; kk < 16; ++kk) {
            u32x4 a = *reinterpret_cast<const u32x4*>(abase + ((aoff + kk * 64) ^ axor));
            acc0 = mfma16x16x32_bf16(a, breg[0][kk], acc0);
            acc1 = mfma16x16x32_bf16(a, breg[1][kk], acc1);
        }
        asm volatile("s_nop 7\n\ts_nop 7" : "+v"(acc0), "+v"(acc1));
        {
            const int rowq = (lane >> 4) * 4;
            #pragma unroll
            for (int r = 0; r < 4; ++r) {
                zb[(kh * 16 + rowq + r) * 132 + ct * 32 + c16]      = acc0[r];
                zb[(kh * 16 + rowq + r) * 132 + ct * 32 + 16 + c16] = acc1[r];
            }
        }
        __syncthreads();

        // --- gates (tid<256) + fire-and-forget tagged h store ---
        if (tid < 256) {
            float zi = zb[ri * 132 + ui]      + zb[(16 + ri) * 132 + ui]      + xv0;
            float zf = zb[ri * 132 + 32 + ui] + zb[(16 + ri) * 132 + 32 + ui] + xv1;
            float zg = zb[ri * 132 + 64 + ui] + zb[(16 + ri) * 132 + 64 + ui] + xv2;
            float zo = zb[ri * 132 + 96 + ui] + zb[(16 + ri) * 132 + 96 + ui] + xv3;
            float ig = fsigmoid(zi), fg = fsigmoid(zf), gg = ftanh(zg), og = fsigmoid(zo);
            creg = fg * creg + ig * gg;
            float hn = og * ftanh(creg);
            unsigned hv = ((unsigned)(s + 1) << 16) | (unsigned)f2bf(hn);
            unsigned int* hwp = hbuf + (size_t)((s + 1) & 1) * (BATCH * UNITS)
                                + (size_t)(r0 + ri) * UNITS + u0 + ui;
            asm volatile("global_store_dword %0, %1, off sc0 sc1" :: "v"(hwp), "v"(hv) : "memory");
            if (s == T_STEPS - 1) out[(size_t)(r0 + ri) * UNITS + u0 + ui] = hn;
        }
        // no barrier: next stage tag-polls
    }
    if (tid < 256) cbuf[(size_t)(r0 + ri) * UNITS + u0 + ui] = creg;
}

// ---------------- launch ----------------

extern "C" void kernel_launch(void* const* d_in, const int* in_sizes, int n_in,
                              void* d_out, int out_size, void* d_ws, size_t ws_size,
                              hipStream_t stream) {
    const float* x    = (const float*)d_in[0];   // [64][512][512]
    const float* Wx   = (const float*)d_in[1];   // [512][4096]
    const float* Wh   = (const float*)d_in[2];   // [1024][4096]
    const float* bias = (const float*)d_in[3];   // [4096]

    char* ws = (char*)d_ws;
    unsigned short* WxT   = (unsigned short*)(ws);                            // 4 MB
    unsigned short* WhT   = (unsigned short*)(ws + (4u << 20));               // 8 MB
    unsigned int*   hbuf  = (unsigned int*)(ws + (12u << 20));                // 512 KB
    float*          cbuf  = (float*)(ws + (12u << 20) + (512u << 10));        // 256 KB
    float*          xz    = (float*)(ws + (13u << 20));                       // T_c MB

    const size_t fixedB = 13u << 20;
    int tc = 1;
    const int cands[9] = {512, 256, 128, 64, 32, 16, 8, 4, 2};
    for (int i = 0; i < 9; ++i)
        if (fixedB + (size_t)cands[i] * (1u << 20) <= ws_size) { tc = cands[i]; break; }

    k_transpose_bf16<<<dim3(128, 16), dim3(32, 32), 0, stream>>>(Wx, WxT, 512, 4096);
    k_transpose_bf16<<<dim3(128, 32), dim3(32, 32), 0, stream>>>(Wh, WhT, 1024, 4096);
    k_init<<<512, 512, 0, stream>>>(hbuf, cbuf);

    const int nch = T_STEPS / tc;
    for (int ci = 0; ci < nch; ++ci) {
        k_xproj<<<dim3(8, tc), 512, 0, stream>>>(x, WxT, bias, xz, ci * tc);
        k_lstm<<<256, 512, 0, stream>>>(xz, WhT, hbuf, cbuf, (float*)d_out,
                                        ci * tc, tc);
    }
}

// Round 12
// 2054.728 us; speedup vs baseline: 1.2553x; 1.2553x over previous
//
#include <hip/hip_runtime.h>
#include <hip/hip_bf16.h>

// BasicLSTM: B=64, T=512, D=512, U=1024.  out = h_last [64][1024] f32.
// Round 12 = R9 (proven 385us/chunk) + barrier-chain cuts:
//  - all-wave flag polling (no post-poll __syncthreads)
//  - packed per-group flags (32 x u32 contiguous = 2 cache lines)
//  - stage loads pipelined vmcnt(2)/vmcnt(0)
// Topology unchanged: 4 m-groups (16 rows) x 32 z-blocks; h staged to
// swizzled LDS via sc0 sc1 (L3-coherent), Wh slice in VGPRs.

#define T_STEPS 512
#define BATCH   64
#define DIM     512
#define UNITS   1024
#define ZCOLS   4096
#define MR      16     // rows per m-group

typedef float        f32x4 __attribute__((ext_vector_type(4)));
typedef unsigned int u32x4 __attribute__((ext_vector_type(4)));

__device__ __forceinline__ f32x4 mfma16x16x32_bf16(u32x4 a, u32x4 b, f32x4 c) {
    asm("v_mfma_f32_16x16x32_bf16 %0, %1, %2, %0" : "+v"(c) : "v"(a), "v"(b));
    return c;
}

__device__ __forceinline__ unsigned short f2bf(float f) {
    union { float f; unsigned u; } v; v.f = f;
    unsigned r = v.u + 0x7fffu + ((v.u >> 16) & 1u);   // RNE
    return (unsigned short)(r >> 16);
}

__device__ __forceinline__ float fsigmoid(float x) { return 1.0f / (1.0f + __expf(-x)); }
__device__ __forceinline__ float ftanh(float x)    { return 1.0f - 2.0f / (__expf(2.0f * x) + 1.0f); }

__device__ __forceinline__ u32x4 pack8(const float* __restrict__ p) {
    float4 f0 = reinterpret_cast<const float4*>(p)[0];
    float4 f1 = reinterpret_cast<const float4*>(p)[1];
    u32x4 r;
    r.x = (unsigned)f2bf(f0.x) | ((unsigned)f2bf(f0.y) << 16);
    r.y = (unsigned)f2bf(f0.z) | ((unsigned)f2bf(f0.w) << 16);
    r.z = (unsigned)f2bf(f1.x) | ((unsigned)f2bf(f1.y) << 16);
    r.w = (unsigned)f2bf(f1.z) | ((unsigned)f2bf(f1.w) << 16);
    return r;
}

#define LD4(d, base) \
    asm volatile("global_load_dwordx4 %0, %1, off sc0 sc1" : "=v"(d) : "v"(base));
#define WAITV(n) \
    asm volatile("s_waitcnt vmcnt(" n ")" ::: "memory"); \
    __builtin_amdgcn_sched_barrier(0);

// ---------------- prep kernels ----------------

__global__ void k_transpose_bf16(const float* __restrict__ in, unsigned short* __restrict__ out,
                                 int K, int N) {
    __shared__ float tile[32][33];
    int n0 = blockIdx.x * 32, k0 = blockIdx.y * 32;
    int tx = threadIdx.x, ty = threadIdx.y;
    tile[ty][tx] = in[(size_t)(k0 + ty) * N + n0 + tx];
    __syncthreads();
    out[(size_t)(n0 + ty) * K + k0 + tx] = f2bf(tile[tx][ty]);
}

__global__ void k_init(unsigned int* __restrict__ hbuf_u32, float* __restrict__ cbuf,
                       unsigned int* __restrict__ flags) {
    int i = blockIdx.x * blockDim.x + threadIdx.x;       // 512*512 threads
    if (i < 65536) hbuf_u32[i] = 0u;                     // 2*64*1024 bf16
    else if (i < 131072) cbuf[i - 65536] = 0.0f;         // 64*1024 f32
    else if (i < 131072 + 4096) flags[i - 131072] = 0u;  // flags (packed, 128 used)
}

// ---------------- phase 1: xz(chunk) = x_t @ Wx + b (proven R8/R9) ----------------
__global__ __launch_bounds__(512, 2) void k_xproj(
        const float* __restrict__ x,
        const unsigned short* __restrict__ WxT,   // [4096][512]
        const float* __restrict__ bias,
        float* __restrict__ xz,                   // [T_c][64][4096]
        int base) {
    const int tid  = threadIdx.x;
    const int lane = tid & 63;
    const int w    = tid >> 6;
    const int n0   = blockIdx.x * 512 + w * 64;
    const int t    = blockIdx.y;
    const int r16  = lane & 15;
    const int kl   = (lane >> 4) * 8;

    __shared__ __align__(16) unsigned short as_[64 * 512];   // 64 KB

    for (int i = tid; i < 4096; i += 512) {
        int row = i >> 6, kc = i & 63;
        u32x4 v = pack8(x + ((size_t)row * T_STEPS + base + t) * DIM + kc * 8);
        int lb = (row * 1024 + kc * 16) ^ ((row & 7) << 4);
        *reinterpret_cast<u32x4*>(reinterpret_cast<char*>(as_) + lb) = v;
    }
    __syncthreads();

    const unsigned short* bp = WxT + (size_t)(n0 + r16) * DIM + kl;

    f32x4 acc[4][4] = {};
    asm volatile("s_nop 1" : "+v"(acc[0][0]), "+v"(acc[1][1]), "+v"(acc[2][2]), "+v"(acc[3][3]));

    #pragma unroll 2
    for (int kk = 0; kk < 16; ++kk) {
        u32x4 b0 = *reinterpret_cast<const u32x4*>(bp + kk * 32);
        u32x4 b1 = *reinterpret_cast<const u32x4*>(bp + 16 * DIM + kk * 32);
        u32x4 b2 = *reinterpret_cast<const u32x4*>(bp + 32 * DIM + kk * 32);
        u32x4 b3 = *reinterpret_cast<const u32x4*>(bp + 48 * DIM + kk * 32);
        u32x4 a[4];
        #pragma unroll
        for (int mt = 0; mt < 4; ++mt) {
            int row = mt * 16 + r16;
            int lb = (row * 1024 + (kk * 32 + kl) * 2) ^ ((row & 7) << 4);
            a[mt] = *reinterpret_cast<const u32x4*>(reinterpret_cast<const char*>(as_) + lb);
        }
        #pragma unroll
        for (int mt = 0; mt < 4; ++mt) {
            acc[mt][0] = mfma16x16x32_bf16(a[mt], b0, acc[mt][0]);
            acc[mt][1] = mfma16x16x32_bf16(a[mt], b1, acc[mt][1]);
            acc[mt][2] = mfma16x16x32_bf16(a[mt], b2, acc[mt][2]);
            acc[mt][3] = mfma16x16x32_bf16(a[mt], b3, acc[mt][3]);
        }
    }
    asm volatile("s_nop 7\n\ts_nop 7" : "+v"(acc[0][0]), "+v"(acc[1][1]), "+v"(acc[2][2]), "+v"(acc[3][3]));

    const int rowq = (lane >> 4) * 4;
    #pragma unroll
    for (int nt = 0; nt < 4; ++nt) {
        const int col = n0 + nt * 16 + r16;
        const float bv = bias[col];
        #pragma unroll
        for (int mt = 0; mt < 4; ++mt)
            #pragma unroll
            for (int r = 0; r < 4; ++r)
                xz[((size_t)t * BATCH + mt * 16 + rowq + r) * ZCOLS + col] = acc[mt][nt][r] + bv;
    }
}

// ---------------- phase 2: batch-grouped recurrence ----------------
// 128 blocks x 512 thr. Block (mg = bid>>5, zb = bid&31): rows [16mg,+16),
// units [32zb,+32) x 4 gates. Waves: ct=w&3 (gate), kh=w>>2 (K half).
__global__ __launch_bounds__(512, 1) void k_lstm(
        const float* __restrict__ xz,            // [T_c][64][4096], bias folded
        const unsigned short* __restrict__ WhT,  // [4096][1024]
        unsigned short* hbuf,                    // [2][64][1024] bf16
        float* __restrict__ cbuf,                // [64][1024] f32
        float* __restrict__ out,                 // [64][1024] f32
        unsigned int* flags,                     // packed: flags[mg*32+zb]
        int base_step, int tc) {
    const int tid  = threadIdx.x;
    const int lane = tid & 63;
    const int w    = tid >> 6;          // 0..7
    const int ct   = w & 3;             // gate
    const int kh   = w >> 2;            // K half
    const int mg   = blockIdx.x >> 5;   // m-group 0..3
    const int zb   = blockIdx.x & 31;   // z-block 0..31
    const int r0   = mg * MR;
    const int u0   = zb * 32;
    const int c16  = lane & 15;
    const int klb  = (lane >> 4) * 16;  // k byte offset within 64B kk-chunk

    __shared__ __align__(16) unsigned short hs[MR * 1024];   // 32 KB, swizzled
    __shared__ float zbuf[2][MR][132];                       // 16.5 KB

    // Wh slice in VGPRs: breg[n][kk] = WhT row ct*1024+u0+n*16+c16,
    // k = kh*512 + kk*32 + (lane>>4)*8
    u32x4 breg[2][16];
    #pragma unroll
    for (int n = 0; n < 2; ++n) {
        const unsigned short* wp =
            WhT + ((size_t)(ct * UNITS + u0 + n * 16 + c16)) * UNITS + kh * 512 + (lane >> 4) * 8;
        #pragma unroll
        for (int kk = 0; kk < 16; ++kk) {
            breg[n][kk] = *reinterpret_cast<const u32x4*>(wp + kk * 32);
            asm volatile("" : "+v"(breg[n][kk]));
        }
    }

    // gate identity: one (row, unit) per thread
    const int ri = tid >> 5;            // 0..15
    const int ui = tid & 31;            // 0..31
    float creg = cbuf[(size_t)(r0 + ri) * UNITS + u0 + ui];

    unsigned int* const myflag = flags + (size_t)blockIdx.x;          // packed
    const unsigned int* const pollp = flags + (size_t)(mg * 32) + (lane & 31);

    for (int t = 0; t < tc; ++t) {
        const int s = base_step + t;
        const unsigned short* hrd = hbuf + (size_t)(s & 1) * (BATCH * UNITS);

        // --- stage group h (16 rows x 1024) -> swizzled LDS, pipelined ---
        {
            u32x4 sv[4];
            #pragma unroll
            for (int j = 0; j < 4; ++j) {
                int i = tid + j * 512;          // 16B-chunk index 0..2047
                int row = i >> 7, kc = i & 127;
                const unsigned short* src = hrd + (size_t)(r0 + row) * UNITS + kc * 8;
                LD4(sv[j], src)
            }
            WAITV("2")
            #pragma unroll
            for (int j = 0; j < 2; ++j) {
                int i = tid + j * 512;
                int row = i >> 7, kc = i & 127;
                int lb = (row * 2048 + kc * 16) ^ ((row & 7) << 4);
                *reinterpret_cast<u32x4*>(reinterpret_cast<char*>(hs) + lb) = sv[j];
            }
            WAITV("0")
            #pragma unroll
            for (int j = 2; j < 4; ++j) {
                int i = tid + j * 512;
                int row = i >> 7, kc = i & 127;
                int lb = (row * 2048 + kc * 16) ^ ((row & 7) << 4);
                *reinterpret_cast<u32x4*>(reinterpret_cast<char*>(hs) + lb) = sv[j];
            }
        }
        __syncthreads();

        // xz prefetch (cached; drains during MFMA phase)
        const float* xp = xz + ((size_t)t * BATCH + r0 + ri) * ZCOLS + u0 + ui;
        float xv0 = xp[0], xv1 = xp[UNITS], xv2 = xp[2 * UNITS], xv3 = xp[3 * UNITS];

        // --- MFMA: 16 kk-steps, A from LDS (shared), B from VGPRs ---
        f32x4 acc0 = {0, 0, 0, 0}, acc1 = {0, 0, 0, 0};
        asm volatile("s_nop 1" : "+v"(acc0), "+v"(acc1));
        const char* abase = reinterpret_cast<const char*>(hs);
        const int axor = (c16 & 7) << 4;
        #pragma unroll
        for (int kk = 0; kk < 16; ++kk) {
            int lb = (c16 * 2048 + kh * 1024 + kk * 64 + klb) ^ axor;
            u32x4 a = *reinterpret_cast<const u32x4*>(abase + lb);
            acc0 = mfma16x16x32_bf16(a, breg[0][kk], acc0);
            acc1 = mfma16x16x32_bf16(a, breg[1][kk], acc1);
        }
        asm volatile("s_nop 7\n\ts_nop 7" : "+v"(acc0), "+v"(acc1));
        {
            const int rowq = (lane >> 4) * 4;
            #pragma unroll
            for (int r = 0; r < 4; ++r) {
                zbuf[kh][rowq + r][ct * 32 + c16]      = acc0[r];
                zbuf[kh][rowq + r][ct * 32 + 16 + c16] = acc1[r];
            }
        }
        __syncthreads();

        // --- gates: all 512 threads, one (ri, ui) each ---
        {
            float zi = zbuf[0][ri][ui]      + zbuf[1][ri][ui]      + xv0;
            float zf = zbuf[0][ri][32 + ui] + zbuf[1][ri][32 + ui] + xv1;
            float zg = zbuf[0][ri][64 + ui] + zbuf[1][ri][64 + ui] + xv2;
            float zo = zbuf[0][ri][96 + ui] + zbuf[1][ri][96 + ui] + xv3;
            float ig = fsigmoid(zi), fg = fsigmoid(zf), gg = ftanh(zg), og = fsigmoid(zo);
            creg = fg * creg + ig * gg;
            float hn = og * ftanh(creg);
            unsigned hv = f2bf(hn);
            unsigned short* hwp = hbuf + (size_t)((s + 1) & 1) * (BATCH * UNITS)
                                  + (size_t)(r0 + ri) * UNITS + u0 + ui;
            asm volatile("global_store_short %0, %1, off sc0 sc1" :: "v"(hwp), "v"(hv) : "memory");
            if (s == T_STEPS - 1) out[(size_t)(r0 + ri) * UNITS + u0 + ui] = hn;
        }

        // --- group barrier: drain + flag + ALL-WAVE poll (no post-sync) ---
        if (t < tc - 1) {
            WAITV("0")                          // own h stores acked (L3)
            __syncthreads();                    // whole block drained
            if (tid == 0) {
                unsigned fv = (unsigned)(s + 1);
                asm volatile("global_store_dword %0, %1, off sc0 sc1"
                             :: "v"(myflag), "v"(fv) : "memory");
            }
            {
                const unsigned tgt = (unsigned)(s + 1);
                int iter = 0;
                for (;;) {
                    unsigned v;
                    asm volatile("global_load_dword %0, %1, off sc0 sc1\n\ts_waitcnt vmcnt(0)"
                                 : "=v"(v) : "v"(pollp) : "memory");
                    if (__all((int)(v >= tgt))) break;
                    if (++iter > (1 << 16)) break;   // fail loud, never hang
                    __builtin_amdgcn_s_sleep(1);
                }
            }
            // no __syncthreads: each wave proceeds to its stage loads;
            // pre-flag sync above is the separator for hs/zbuf reuse.
        }
    }
    cbuf[(size_t)(r0 + ri) * UNITS + u0 + ui] = creg;
}

// ---------------- launch ----------------

extern "C" void kernel_launch(void* const* d_in, const int* in_sizes, int n_in,
                              void* d_out, int out_size, void* d_ws, size_t ws_size,
                              hipStream_t stream) {
    const float* x    = (const float*)d_in[0];   // [64][512][512]
    const float* Wx   = (const float*)d_in[1];   // [512][4096]
    const float* Wh   = (const float*)d_in[2];   // [1024][4096]
    const float* bias = (const float*)d_in[3];   // [4096]

    char* ws = (char*)d_ws;
    unsigned short* WxT   = (unsigned short*)(ws);                            // 4 MB
    unsigned short* WhT   = (unsigned short*)(ws + (4u << 20));               // 8 MB
    unsigned short* hbuf  = (unsigned short*)(ws + (12u << 20));              // 256 KB
    float*          cbuf  = (float*)(ws + (12u << 20) + (256u << 10));        // 256 KB
    unsigned int*   flags = (unsigned int*)(ws + (12u << 20) + (512u << 10)); // 16 KB
    float*          xz    = (float*)(ws + (13u << 20));                       // T_c MB

    const size_t fixedB = 13u << 20;
    int tc = 1;
    const int cands[9] = {512, 256, 128, 64, 32, 16, 8, 4, 2};
    for (int i = 0; i < 9; ++i)
        if (fixedB + (size_t)cands[i] * (1u << 20) <= ws_size) { tc = cands[i]; break; }

    k_transpose_bf16<<<dim3(128, 16), dim3(32, 32), 0, stream>>>(Wx, WxT, 512, 4096);
    k_transpose_bf16<<<dim3(128, 32), dim3(32, 32), 0, stream>>>(Wh, WhT, 1024, 4096);
    k_init<<<512, 512, 0, stream>>>((unsigned int*)hbuf, cbuf, flags);

    const int nch = T_STEPS / tc;
    for (int ci = 0; ci < nch; ++ci) {
        k_xproj<<<dim3(8, tc), 512, 0, stream>>>(x, WxT, bias, xz, ci * tc);
        k_lstm<<<128, 512, 0, stream>>>(xz, WhT, hbuf, cbuf, (float*)d_out, flags,
                                        ci * tc, tc);
    }
}